// Round 9
// baseline (236.330 us; speedup 1.0000x reference)
//
#include <hip/hip_runtime.h>

// Problem constants (B=2, S=2048, D=1024, H=16, HD=64). fp32 in / fp32 out.
#define NB 2
#define NS 2048
#define ND 1024
#define NH 16
#define NHD 64
#define QLD (3 * ND)   // qkv workspace row stride in elements = 3072
#define PADP 72        // Ps row stride (u16); 144 B = 16B-aligned rows
#define PADV 68        // Vt row stride (u16)

typedef unsigned short u16;
typedef __attribute__((ext_vector_type(8))) short short8;   // 8 x bf16 (4 VGPRs)
typedef __attribute__((ext_vector_type(4))) short short4v;  // 4 x bf16 (2 VGPRs)
typedef __attribute__((ext_vector_type(4))) float f32x4;

__device__ __forceinline__ u16 f2b(float f) {
    unsigned int x = __float_as_uint(f);
    return (u16)((x + 0x7fffu + ((x >> 16) & 1u)) >> 16);  // RNE
}

// ---------------------------------------------------------------------------
// fp32 -> bf16 elementwise cast (for x). n must be a multiple of 8.
__global__ __launch_bounds__(256) void convert_bf16(
    const float* __restrict__ src, u16* __restrict__ dst, int n)
{
    const int i = (blockIdx.x * 256 + threadIdx.x) * 8;
    if (i >= n) return;
    float4 a = *(const float4*)(src + i);
    float4 b = *(const float4*)(src + i + 4);
    *(ushort4*)(dst + i)     = make_ushort4(f2b(a.x), f2b(a.y), f2b(a.z), f2b(a.w));
    *(ushort4*)(dst + i + 4) = make_ushort4(f2b(b.x), f2b(b.y), f2b(b.z), f2b(b.w));
}

// ---------------------------------------------------------------------------
// W[K,N] fp32 -> WT[N,K] bf16 (64x64 tiles via LDS).
__global__ __launch_bounds__(256) void transpose_bf16(
    const float* __restrict__ W, u16* __restrict__ WT, int K, int N)
{
    __shared__ u16 Ts[64 * 72];
    const int t = threadIdx.x;
    const int k0 = blockIdx.y << 6, n0 = blockIdx.x << 6;
    const int r = t >> 4, c = (t & 15) << 2;
    #pragma unroll
    for (int rr = 0; rr < 64; rr += 16) {
        float4 v = *(const float4*)&W[(size_t)(k0 + r + rr) * N + n0 + c];
        Ts[(c + 0) * 72 + r + rr] = f2b(v.x);
        Ts[(c + 1) * 72 + r + rr] = f2b(v.y);
        Ts[(c + 2) * 72 + r + rr] = f2b(v.z);
        Ts[(c + 3) * 72 + r + rr] = f2b(v.w);
    }
    __syncthreads();
    const int n = t >> 2, cc = (t & 3) << 4;
    uint4 a = *(const uint4*)&Ts[n * 72 + cc];
    uint4 b = *(const uint4*)&Ts[n * 72 + cc + 8];
    *(uint4*)&WT[(size_t)(n0 + n) * K + k0 + cc]     = a;
    *(uint4*)&WT[(size_t)(n0 + n) * K + k0 + cc + 8] = b;
}

// ---------------------------------------------------------------------------
// bf16 MFMA GEMM: C[M,N] = A[M,K] @ BT[N,K]^T + bias[N].
// BM=128 x BN (template) tile, 256 threads, BK=32, global_load_lds w=16,
// XOR-swizzled LDS. MFMA operands SWAPPED (A-op=B-frag, B-op=A-frag) so the
// C/D lane layout is transposed: lane owns one m (=col) and 4 consecutive n
// (=quad*4+reg) -> vectorized ushort4/float4 epilogue stores (the 4 quads of
// a col cover 32 contiguous bytes of row m).
template <bool STORE_BF16, int BN>
__global__ __launch_bounds__(256) void gemm_mfma(
    const u16* __restrict__ A, const u16* __restrict__ BT,
    const float* __restrict__ bias,
    void* __restrict__ C, int M, int N, int K)
{
    constexpr int WN  = BN / 2;          // cols per wave
    constexpr int JN  = WN / 16;         // B-fragments per wave
    constexpr int NBI = (BN * 4) / 256;  // B-staging DMA issues

    __shared__ u16 As[128 * 32];
    __shared__ u16 Bs[BN * 32];

    const int tid = threadIdx.x;
    const int wave = tid >> 6, lane = tid & 63;
    const int col = lane & 15, quad = lane >> 4;
    const int wm = wave >> 1, wn = wave & 1;
    const int row0 = blockIdx.y << 7, col0 = blockIdx.x * BN;

    f32x4 acc[4][JN] = {};

    const u16* asrc[2];
    u16* adst[2];
    #pragma unroll
    for (int is = 0; is < 2; ++is) {
        const int J = is * 256 + wave * 64 + lane;
        const int m = J >> 2;
        const int q = (J & 3) ^ ((m >> 1) & 3);
        asrc[is] = A + (size_t)(row0 + m) * K + q * 8;
        adst[is] = &As[(size_t)(is * 256 + wave * 64) * 8];
    }
    const u16* bsrc[NBI];
    u16* bdst[NBI];
    #pragma unroll
    for (int is = 0; is < NBI; ++is) {
        const int J = is * 256 + wave * 64 + lane;
        const int m = J >> 2;
        const int q = (J & 3) ^ ((m >> 1) & 3);
        bsrc[is] = BT + (size_t)(col0 + m) * K + q * 8;
        bdst[is] = &Bs[(size_t)(is * 256 + wave * 64) * 8];
    }

    for (int kk = 0; kk < K; kk += 32) {
        __syncthreads();
        #pragma unroll
        for (int is = 0; is < 2; ++is)
            __builtin_amdgcn_global_load_lds(
                (const __attribute__((address_space(1))) unsigned int*)(asrc[is] + kk),
                (__attribute__((address_space(3))) unsigned int*)adst[is], 16, 0, 0);
        #pragma unroll
        for (int is = 0; is < NBI; ++is)
            __builtin_amdgcn_global_load_lds(
                (const __attribute__((address_space(1))) unsigned int*)(bsrc[is] + kk),
                (__attribute__((address_space(3))) unsigned int*)bdst[is], 16, 0, 0);
        __syncthreads();

        short8 af[4], bf[JN];
        #pragma unroll
        for (int i = 0; i < 4; ++i) {
            const int m = wm * 64 + i * 16 + col;
            af[i] = *(const short8*)&As[(m * 4 + (quad ^ ((m >> 1) & 3))) * 8];
        }
        #pragma unroll
        for (int j = 0; j < JN; ++j) {
            const int n = wn * WN + j * 16 + col;
            bf[j] = *(const short8*)&Bs[(n * 4 + (quad ^ ((n >> 1) & 3))) * 8];
        }
        #pragma unroll
        for (int i = 0; i < 4; ++i)
            #pragma unroll
            for (int j = 0; j < JN; ++j)
                acc[i][j] = __builtin_amdgcn_mfma_f32_16x16x32_bf16(
                    bf[j], af[i], acc[i][j], 0, 0, 0);   // swapped: D is C^T-layout
    }

    // epilogue: lane writes C[gm][gn..gn+3], gm = row0+wm*64+i*16+col,
    // gn = col0+wn*WN+j*16+quad*4  (4 consecutive n per lane -> 8/16 B stores)
    #pragma unroll
    for (int i = 0; i < 4; ++i) {
        const int gm = row0 + wm * 64 + i * 16 + col;
        #pragma unroll
        for (int j = 0; j < JN; ++j) {
            const int gn = col0 + wn * WN + j * 16 + quad * 4;
            float4 bj = *(const float4*)(bias + gn);
            float v0 = acc[i][j][0] + bj.x;
            float v1 = acc[i][j][1] + bj.y;
            float v2 = acc[i][j][2] + bj.z;
            float v3 = acc[i][j][3] + bj.w;
            if (STORE_BF16) {
                *(ushort4*)((u16*)C + (size_t)gm * N + gn) =
                    make_ushort4(f2b(v0), f2b(v1), f2b(v2), f2b(v3));
            } else {
                *(float4*)((float*)C + (size_t)gm * N + gn) =
                    make_float4(v0, v1, v2, v3);
            }
        }
    }
}

// ---------------------------------------------------------------------------
// MFMA flash attention: causal pairing + transposed-S softmax + K/V prefetch.
// (unchanged from R8 - 68 us, passed)
__global__ __launch_bounds__(256) void attn_kernel(
    const u16* __restrict__ qkv, u16* __restrict__ vals)
{
    __shared__ u16 Ks[2][64 * 64];    // 2 x 8 KB, XOR-swizzled 16B chunks
    __shared__ u16 Vt[2][64 * PADV];  // 2 x 8.5 KB, transposed V
    __shared__ u16 Ps[64 * PADP];     // 9 KB, per-wave 16-row strips

    const int tid = threadIdx.x;
    const int wave = tid >> 6, lane = tid & 63;
    const int col = lane & 15, quad = lane >> 4;
    const int qtA = blockIdx.x;          // 0..15
    const int qtB = 31 - qtA;            // 16..31
    const int bh = blockIdx.y;
    const int b = bh >> 4, h = bh & 15;
    const size_t base = (size_t)b * NS * QLD + (size_t)h * (3 * NHD);
    const int q0 = wave * 16;
    const int qloc = q0 + col;           // this lane's query (tile-local)

    int Jrow[2], Jcol[2];
    #pragma unroll
    for (int is = 0; is < 2; ++is) {
        const int J = is * 256 + wave * 64 + lane;
        Jrow[is] = J >> 3;
        Jcol[is] = ((J & 7) ^ (Jrow[is] & 7)) << 3;
    }

    auto stage_tile = [&](int buf, int srow, int coloff) {
        #pragma unroll
        for (int is = 0; is < 2; ++is) {
            __builtin_amdgcn_global_load_lds(
                (const __attribute__((address_space(1))) unsigned int*)
                    (qkv + base + (size_t)(srow + Jrow[is]) * QLD + coloff + Jcol[is]),
                (__attribute__((address_space(3))) unsigned int*)
                    &Ks[buf][(size_t)(is * 256 + wave * 64) * 8], 16, 0, 0);
        }
    };
    auto read_frag = [&](int buf, int row, int half) -> short8 {
        const int blk = row * 8 + ((quad + (half << 2)) ^ (row & 7));
        return *(const short8*)&Ks[buf][blk << 3];
    };

    const int vtx = tid & 15, vty = tid >> 4;
    const int vk0 = vty << 2, vd0 = vtx << 2;
    auto load_vregs = [&](int kt, ushort4* vr) {
        const u16* vsrc = qkv + base + (size_t)(kt * 64 + vk0) * QLD + 2 * NHD + vd0;
        vr[0] = *(const ushort4*)(vsrc);
        vr[1] = *(const ushort4*)(vsrc + QLD);
        vr[2] = *(const ushort4*)(vsrc + 2 * QLD);
        vr[3] = *(const ushort4*)(vsrc + 3 * QLD);
    };
    auto write_vt = [&](int buf, const ushort4* vr) {
        *(ushort4*)&Vt[buf][(vd0 + 0) * PADV + vk0] =
            make_ushort4(vr[0].x, vr[1].x, vr[2].x, vr[3].x);
        *(ushort4*)&Vt[buf][(vd0 + 1) * PADV + vk0] =
            make_ushort4(vr[0].y, vr[1].y, vr[2].y, vr[3].y);
        *(ushort4*)&Vt[buf][(vd0 + 2) * PADV + vk0] =
            make_ushort4(vr[0].z, vr[1].z, vr[2].z, vr[3].z);
        *(ushort4*)&Vt[buf][(vd0 + 3) * PADV + vk0] =
            make_ushort4(vr[0].w, vr[1].w, vr[2].w, vr[3].w);
    };

    // ---- prologue: stage Q_A -> Ks[0], Q_B -> Ks[1]; hoist B-fragments ----
    stage_tile(0, qtA * 64, 0);
    stage_tile(1, qtB * 64, 0);
    __syncthreads();
    short8 bqA0 = read_frag(0, qloc, 0), bqA1 = read_frag(0, qloc, 1);
    short8 bqB0 = read_frag(1, qloc, 0), bqB1 = read_frag(1, qloc, 1);
    __syncthreads();                     // Q reads done before K(0) overwrites

    f32x4 accA[4] = {}, accB[4] = {};
    float mA = -1e30f, lA = 0.f, mB = -1e30f, lB = 0.f;

    auto process = [&](const short8& b0, const short8& b1,
                       short8 (*kb)[2], short8 (*vb)[2],
                       f32x4* accO, float& m, float& l, bool diag) {
        f32x4 s[4] = {};
        #pragma unroll
        for (int kg = 0; kg < 4; ++kg) {
            s[kg] = __builtin_amdgcn_mfma_f32_16x16x32_bf16(kb[kg][0], b0, s[kg], 0, 0, 0);
            s[kg] = __builtin_amdgcn_mfma_f32_16x16x32_bf16(kb[kg][1], b1, s[kg], 0, 0, 0);
        }
        #pragma unroll
        for (int kg = 0; kg < 4; ++kg)
            #pragma unroll
            for (int r = 0; r < 4; ++r) {
                float v = s[kg][r] * 0.125f;
                if (diag && (kg * 16 + quad * 4 + r > qloc)) v = -1e30f;
                s[kg][r] = v;
            }
        float mx = -1e30f;
        #pragma unroll
        for (int kg = 0; kg < 4; ++kg)
            mx = fmaxf(mx, fmaxf(fmaxf(s[kg][0], s[kg][1]), fmaxf(s[kg][2], s[kg][3])));
        mx = fmaxf(mx, __shfl_xor(mx, 16, 64));
        mx = fmaxf(mx, __shfl_xor(mx, 32, 64));
        const float mn = fmaxf(m, mx);
        const float alpha = __expf(m - mn);
        m = mn;

        float ps = 0.f;
        #pragma unroll
        for (int kg = 0; kg < 4; ++kg) {
            float p0 = __expf(s[kg][0] - mn);
            float p1 = __expf(s[kg][1] - mn);
            float p2 = __expf(s[kg][2] - mn);
            float p3 = __expf(s[kg][3] - mn);
            ps += (p0 + p1) + (p2 + p3);
            *(ushort4*)&Ps[qloc * PADP + kg * 16 + quad * 4] =
                make_ushort4(f2b(p0), f2b(p1), f2b(p2), f2b(p3));
        }
        ps += __shfl_xor(ps, 16, 64);
        ps += __shfl_xor(ps, 32, 64);
        l = l * alpha + ps;
        #pragma unroll
        for (int dg = 0; dg < 4; ++dg)
            #pragma unroll
            for (int r = 0; r < 4; ++r) accO[dg][r] *= alpha;

        short8 pb0 = *(const short8*)&Ps[qloc * PADP + quad * 8];
        short8 pb1 = *(const short8*)&Ps[qloc * PADP + 32 + quad * 8];
        #pragma unroll
        for (int dg = 0; dg < 4; ++dg) {
            accO[dg] = __builtin_amdgcn_mfma_f32_16x16x32_bf16(vb[dg][0], pb0, accO[dg], 0, 0, 0);
            accO[dg] = __builtin_amdgcn_mfma_f32_16x16x32_bf16(vb[dg][1], pb1, accO[dg], 0, 0, 0);
        }
    };

    // ---- software pipeline ----
    ushort4 vcur[4], vnxt[4];
    stage_tile(0, 0, NHD);               // K(0) -> Ks[0]
    load_vregs(0, vcur);

    for (int kt = 0; kt <= qtB; ++kt) {
        const int cur = kt & 1, nxt = cur ^ 1;
        __syncthreads();                 // (A) drains K(kt) DMA (aged a phase)
        write_vt(cur, vcur);
        __syncthreads();                 // (B) Vt[cur] visible
        if (kt < qtB) {
            stage_tile(nxt, (kt + 1) * 64, NHD);  // in flight during compute
            load_vregs(kt + 1, vnxt);
        }

        short8 kb[4][2], vb[4][2];
        #pragma unroll
        for (int kg = 0; kg < 4; ++kg) {
            kb[kg][0] = read_frag(cur, kg * 16 + col, 0);
            kb[kg][1] = read_frag(cur, kg * 16 + col, 1);
        }
        #pragma unroll
        for (int dg = 0; dg < 4; ++dg) {
            const int n = dg * 16 + col;
            short4v lo0 = *(const short4v*)&Vt[cur][n * PADV + quad * 8];
            short4v hi0 = *(const short4v*)&Vt[cur][n * PADV + quad * 8 + 4];
            short4v lo1 = *(const short4v*)&Vt[cur][n * PADV + 32 + quad * 8];
            short4v hi1 = *(const short4v*)&Vt[cur][n * PADV + 32 + quad * 8 + 4];
            vb[dg][0] = __builtin_shufflevector(lo0, hi0, 0, 1, 2, 3, 4, 5, 6, 7);
            vb[dg][1] = __builtin_shufflevector(lo1, hi1, 0, 1, 2, 3, 4, 5, 6, 7);
        }

        process(bqB0, bqB1, kb, vb, accB, mB, lB, kt == qtB);
        if (kt <= qtA)
            process(bqA0, bqA1, kb, vb, accA, mA, lA, kt == qtA);

        #pragma unroll
        for (int i = 0; i < 4; ++i) vcur[i] = vnxt[i];
    }

    // ---- epilogue ----
    {
        const float inv = 1.f / lA;
        const size_t rowoff = ((size_t)b * NS + qtA * 64 + qloc) * ND + h * NHD;
        #pragma unroll
        for (int dg = 0; dg < 4; ++dg) {
            ushort4 o;
            o.x = f2b(accA[dg][0] * inv);
            o.y = f2b(accA[dg][1] * inv);
            o.z = f2b(accA[dg][2] * inv);
            o.w = f2b(accA[dg][3] * inv);
            *(ushort4*)(vals + rowoff + dg * 16 + quad * 4) = o;
        }
    }
    {
        const float inv = 1.f / lB;
        const size_t rowoff = ((size_t)b * NS + qtB * 64 + qloc) * ND + h * NHD;
        #pragma unroll
        for (int dg = 0; dg < 4; ++dg) {
            ushort4 o;
            o.x = f2b(accB[dg][0] * inv);
            o.y = f2b(accB[dg][1] * inv);
            o.z = f2b(accB[dg][2] * inv);
            o.w = f2b(accB[dg][3] * inv);
            *(ushort4*)(vals + rowoff + dg * 16 + quad * 4) = o;
        }
    }
}

extern "C" void kernel_launch(void* const* d_in, const int* in_sizes, int n_in,
                              void* d_out, int out_size, void* d_ws, size_t ws_size,
                              hipStream_t stream)
{
    // inputs: x, mask(unused), W_qkv, b_qkv, W_o, b_o  -- all fp32
    const float* x    = (const float*)d_in[0];
    const float* Wqkv = (const float*)d_in[2];
    const float* bqkv = (const float*)d_in[3];
    const float* Wo   = (const float*)d_in[4];
    const float* bo   = (const float*)d_in[5];
    float* out = (float*)d_out;

    u16* x_bf   = (u16*)d_ws;                       //  4096*1024
    u16* WqkvT  = x_bf   + (size_t)4096 * 1024;     //  3072*1024  [N,K]
    u16* WoT    = WqkvT  + (size_t)3072 * 1024;     //  1024*1024  [N,K]
    u16* qkv    = WoT    + (size_t)1024 * 1024;     //  4096*3072
    u16* vals   = qkv    + (size_t)4096 * 3072;     //  4096*1024

    const int M = NB * NS;  // 4096

    convert_bf16<<<dim3(M * ND / (256 * 8)), dim3(256), 0, stream>>>(
        x, x_bf, M * ND);
    transpose_bf16<<<dim3(QLD / 64, ND / 64), dim3(256), 0, stream>>>(
        Wqkv, WqkvT, ND, QLD);
    transpose_bf16<<<dim3(ND / 64, ND / 64), dim3(256), 0, stream>>>(
        Wo, WoT, ND, ND);

    gemm_mfma<true, 128><<<dim3(QLD / 128, M / 128), dim3(256), 0, stream>>>(
        x_bf, WqkvT, bqkv, qkv, M, QLD, ND);
    attn_kernel<<<dim3(16, NB * NH), dim3(256), 0, stream>>>(qkv, vals);
    gemm_mfma<false, 64><<<dim3(ND / 64, M / 128), dim3(256), 0, stream>>>(
        vals, WoT, bo, out, M, ND, ND);
}

// Round 10
// 233.127 us; speedup vs baseline: 1.0137x; 1.0137x over previous
//
#include <hip/hip_runtime.h>

// Problem constants (B=2, S=2048, D=1024, H=16, HD=64). fp32 in / fp32 out.
#define NB 2
#define NS 2048
#define ND 1024
#define NH 16
#define NHD 64
#define QLD (3 * ND)   // qkv workspace row stride in elements = 3072
#define PADP 72        // Ps row stride (u16); 144 B = 16B-aligned rows
#define PADV 68        // Vt row stride (u16)

typedef unsigned short u16;
typedef __attribute__((ext_vector_type(8))) short short8;   // 8 x bf16 (4 VGPRs)
typedef __attribute__((ext_vector_type(4))) short short4v;  // 4 x bf16 (2 VGPRs)
typedef __attribute__((ext_vector_type(4))) float f32x4;

__device__ __forceinline__ u16 f2b(float f) {
    unsigned int x = __float_as_uint(f);
    return (u16)((x + 0x7fffu + ((x >> 16) & 1u)) >> 16);  // RNE
}

// ---------------------------------------------------------------------------
// fp32 -> bf16 elementwise cast (for x). n must be a multiple of 8.
__global__ __launch_bounds__(256) void convert_bf16(
    const float* __restrict__ src, u16* __restrict__ dst, int n)
{
    const int i = (blockIdx.x * 256 + threadIdx.x) * 8;
    if (i >= n) return;
    float4 a = *(const float4*)(src + i);
    float4 b = *(const float4*)(src + i + 4);
    *(ushort4*)(dst + i)     = make_ushort4(f2b(a.x), f2b(a.y), f2b(a.z), f2b(a.w));
    *(ushort4*)(dst + i + 4) = make_ushort4(f2b(b.x), f2b(b.y), f2b(b.z), f2b(b.w));
}

// ---------------------------------------------------------------------------
// W[K,N] fp32 -> WT[N,K] bf16 (64x64 tiles via LDS).
__global__ __launch_bounds__(256) void transpose_bf16(
    const float* __restrict__ W, u16* __restrict__ WT, int K, int N)
{
    __shared__ u16 Ts[64 * 72];
    const int t = threadIdx.x;
    const int k0 = blockIdx.y << 6, n0 = blockIdx.x << 6;
    const int r = t >> 4, c = (t & 15) << 2;
    #pragma unroll
    for (int rr = 0; rr < 64; rr += 16) {
        float4 v = *(const float4*)&W[(size_t)(k0 + r + rr) * N + n0 + c];
        Ts[(c + 0) * 72 + r + rr] = f2b(v.x);
        Ts[(c + 1) * 72 + r + rr] = f2b(v.y);
        Ts[(c + 2) * 72 + r + rr] = f2b(v.z);
        Ts[(c + 3) * 72 + r + rr] = f2b(v.w);
    }
    __syncthreads();
    const int n = t >> 2, cc = (t & 3) << 4;
    uint4 a = *(const uint4*)&Ts[n * 72 + cc];
    uint4 b = *(const uint4*)&Ts[n * 72 + cc + 8];
    *(uint4*)&WT[(size_t)(n0 + n) * K + k0 + cc]     = a;
    *(uint4*)&WT[(size_t)(n0 + n) * K + k0 + cc + 8] = b;
}

// ---------------------------------------------------------------------------
// bf16 MFMA GEMM, double-buffered single-barrier K-loop:
// C[M,N] = A[M,K] @ BT[N,K]^T + bias[N].  128x128 tile, 256 threads, BK=32,
// global_load_lds w=16, XOR-swizzled LDS.
// Per iteration: one __syncthreads() (drains the DMA issued a FULL compute
// phase earlier -> cheap), then issue DMA(kk+32) into the other buffer, then
// ds_read + 16 MFMA on the current buffer. Hazards: reads of buffer b always
// complete before the barrier preceding the DMA that overwrites b.
// MFMA operands swapped (D = C^T layout): lane owns one m (=col) and 4
// consecutive n (=quad*4+r) -> vectorized ushort4/float4 epilogue stores.
template <bool STORE_BF16>
__global__ __launch_bounds__(256) void gemm_mfma(
    const u16* __restrict__ A, const u16* __restrict__ BT,
    const float* __restrict__ bias,
    void* __restrict__ C, int M, int N, int K)
{
    __shared__ u16 As[2][128 * 32];   // 2 x 8 KB
    __shared__ u16 Bs[2][128 * 32];

    const int tid = threadIdx.x;
    const int wave = tid >> 6, lane = tid & 63;
    const int col = lane & 15, quad = lane >> 4;
    const int wm = wave >> 1, wn = wave & 1;
    const int row0 = blockIdx.y << 7, col0 = blockIdx.x << 7;

    f32x4 acc[4][4] = {};

    const u16* asrc[2];
    const u16* bsrc[2];
    int dstoff[2];
    #pragma unroll
    for (int is = 0; is < 2; ++is) {
        const int J = is * 256 + wave * 64 + lane;
        const int m = J >> 2;
        const int q = (J & 3) ^ ((m >> 1) & 3);
        asrc[is] = A  + (size_t)(row0 + m) * K + q * 8;
        bsrc[is] = BT + (size_t)(col0 + m) * K + q * 8;
        dstoff[is] = (is * 256 + wave * 64) * 8;     // wave-uniform (u16 elems)
    }

    auto stage = [&](int buf, int kk) {
        #pragma unroll
        for (int is = 0; is < 2; ++is) {
            __builtin_amdgcn_global_load_lds(
                (const __attribute__((address_space(1))) unsigned int*)(asrc[is] + kk),
                (__attribute__((address_space(3))) unsigned int*)&As[buf][dstoff[is]],
                16, 0, 0);
            __builtin_amdgcn_global_load_lds(
                (const __attribute__((address_space(1))) unsigned int*)(bsrc[is] + kk),
                (__attribute__((address_space(3))) unsigned int*)&Bs[buf][dstoff[is]],
                16, 0, 0);
        }
    };

    stage(0, 0);                       // cold prologue DMA
    int ib = 0;
    for (int kk = 0; kk < K; kk += 32, ib ^= 1) {
        __syncthreads();               // drains DMA(ib) (aged one compute phase)
        if (kk + 32 < K)
            stage(ib ^ 1, kk + 32);    // lands during this iteration's compute

        short8 af[4], bf[4];
        #pragma unroll
        for (int i = 0; i < 4; ++i) {
            const int m = wm * 64 + i * 16 + col;
            af[i] = *(const short8*)&As[ib][(m * 4 + (quad ^ ((m >> 1) & 3))) * 8];
        }
        #pragma unroll
        for (int j = 0; j < 4; ++j) {
            const int n = wn * 64 + j * 16 + col;
            bf[j] = *(const short8*)&Bs[ib][(n * 4 + (quad ^ ((n >> 1) & 3))) * 8];
        }
        #pragma unroll
        for (int i = 0; i < 4; ++i)
            #pragma unroll
            for (int j = 0; j < 4; ++j)
                acc[i][j] = __builtin_amdgcn_mfma_f32_16x16x32_bf16(
                    bf[j], af[i], acc[i][j], 0, 0, 0);   // swapped: D = C^T layout
    }

    // epilogue: lane writes C[gm][gn..gn+3]
    #pragma unroll
    for (int i = 0; i < 4; ++i) {
        const int gm = row0 + wm * 64 + i * 16 + col;
        #pragma unroll
        for (int j = 0; j < 4; ++j) {
            const int gn = col0 + wn * 64 + j * 16 + quad * 4;
            float4 bj = *(const float4*)(bias + gn);
            float v0 = acc[i][j][0] + bj.x;
            float v1 = acc[i][j][1] + bj.y;
            float v2 = acc[i][j][2] + bj.z;
            float v3 = acc[i][j][3] + bj.w;
            if (STORE_BF16) {
                *(ushort4*)((u16*)C + (size_t)gm * N + gn) =
                    make_ushort4(f2b(v0), f2b(v1), f2b(v2), f2b(v3));
            } else {
                *(float4*)((float*)C + (size_t)gm * N + gn) =
                    make_float4(v0, v1, v2, v3);
            }
        }
    }
}

// ---------------------------------------------------------------------------
// MFMA flash attention: causal pairing + transposed-S softmax + K/V prefetch.
// (unchanged from R8 - 68 us, passed)
__global__ __launch_bounds__(256) void attn_kernel(
    const u16* __restrict__ qkv, u16* __restrict__ vals)
{
    __shared__ u16 Ks[2][64 * 64];    // 2 x 8 KB, XOR-swizzled 16B chunks
    __shared__ u16 Vt[2][64 * PADV];  // 2 x 8.5 KB, transposed V
    __shared__ u16 Ps[64 * PADP];     // 9 KB, per-wave 16-row strips

    const int tid = threadIdx.x;
    const int wave = tid >> 6, lane = tid & 63;
    const int col = lane & 15, quad = lane >> 4;
    const int qtA = blockIdx.x;          // 0..15
    const int qtB = 31 - qtA;            // 16..31
    const int bh = blockIdx.y;
    const int b = bh >> 4, h = bh & 15;
    const size_t base = (size_t)b * NS * QLD + (size_t)h * (3 * NHD);
    const int q0 = wave * 16;
    const int qloc = q0 + col;           // this lane's query (tile-local)

    int Jrow[2], Jcol[2];
    #pragma unroll
    for (int is = 0; is < 2; ++is) {
        const int J = is * 256 + wave * 64 + lane;
        Jrow[is] = J >> 3;
        Jcol[is] = ((J & 7) ^ (Jrow[is] & 7)) << 3;
    }

    auto stage_tile = [&](int buf, int srow, int coloff) {
        #pragma unroll
        for (int is = 0; is < 2; ++is) {
            __builtin_amdgcn_global_load_lds(
                (const __attribute__((address_space(1))) unsigned int*)
                    (qkv + base + (size_t)(srow + Jrow[is]) * QLD + coloff + Jcol[is]),
                (__attribute__((address_space(3))) unsigned int*)
                    &Ks[buf][(size_t)(is * 256 + wave * 64) * 8], 16, 0, 0);
        }
    };
    auto read_frag = [&](int buf, int row, int half) -> short8 {
        const int blk = row * 8 + ((quad + (half << 2)) ^ (row & 7));
        return *(const short8*)&Ks[buf][blk << 3];
    };

    const int vtx = tid & 15, vty = tid >> 4;
    const int vk0 = vty << 2, vd0 = vtx << 2;
    auto load_vregs = [&](int kt, ushort4* vr) {
        const u16* vsrc = qkv + base + (size_t)(kt * 64 + vk0) * QLD + 2 * NHD + vd0;
        vr[0] = *(const ushort4*)(vsrc);
        vr[1] = *(const ushort4*)(vsrc + QLD);
        vr[2] = *(const ushort4*)(vsrc + 2 * QLD);
        vr[3] = *(const ushort4*)(vsrc + 3 * QLD);
    };
    auto write_vt = [&](int buf, const ushort4* vr) {
        *(ushort4*)&Vt[buf][(vd0 + 0) * PADV + vk0] =
            make_ushort4(vr[0].x, vr[1].x, vr[2].x, vr[3].x);
        *(ushort4*)&Vt[buf][(vd0 + 1) * PADV + vk0] =
            make_ushort4(vr[0].y, vr[1].y, vr[2].y, vr[3].y);
        *(ushort4*)&Vt[buf][(vd0 + 2) * PADV + vk0] =
            make_ushort4(vr[0].z, vr[1].z, vr[2].z, vr[3].z);
        *(ushort4*)&Vt[buf][(vd0 + 3) * PADV + vk0] =
            make_ushort4(vr[0].w, vr[1].w, vr[2].w, vr[3].w);
    };

    // ---- prologue: stage Q_A -> Ks[0], Q_B -> Ks[1]; hoist B-fragments ----
    stage_tile(0, qtA * 64, 0);
    stage_tile(1, qtB * 64, 0);
    __syncthreads();
    short8 bqA0 = read_frag(0, qloc, 0), bqA1 = read_frag(0, qloc, 1);
    short8 bqB0 = read_frag(1, qloc, 0), bqB1 = read_frag(1, qloc, 1);
    __syncthreads();                     // Q reads done before K(0) overwrites

    f32x4 accA[4] = {}, accB[4] = {};
    float mA = -1e30f, lA = 0.f, mB = -1e30f, lB = 0.f;

    auto process = [&](const short8& b0, const short8& b1,
                       short8 (*kb)[2], short8 (*vb)[2],
                       f32x4* accO, float& m, float& l, bool diag) {
        f32x4 s[4] = {};
        #pragma unroll
        for (int kg = 0; kg < 4; ++kg) {
            s[kg] = __builtin_amdgcn_mfma_f32_16x16x32_bf16(kb[kg][0], b0, s[kg], 0, 0, 0);
            s[kg] = __builtin_amdgcn_mfma_f32_16x16x32_bf16(kb[kg][1], b1, s[kg], 0, 0, 0);
        }
        #pragma unroll
        for (int kg = 0; kg < 4; ++kg)
            #pragma unroll
            for (int r = 0; r < 4; ++r) {
                float v = s[kg][r] * 0.125f;
                if (diag && (kg * 16 + quad * 4 + r > qloc)) v = -1e30f;
                s[kg][r] = v;
            }
        float mx = -1e30f;
        #pragma unroll
        for (int kg = 0; kg < 4; ++kg)
            mx = fmaxf(mx, fmaxf(fmaxf(s[kg][0], s[kg][1]), fmaxf(s[kg][2], s[kg][3])));
        mx = fmaxf(mx, __shfl_xor(mx, 16, 64));
        mx = fmaxf(mx, __shfl_xor(mx, 32, 64));
        const float mn = fmaxf(m, mx);
        const float alpha = __expf(m - mn);
        m = mn;

        float ps = 0.f;
        #pragma unroll
        for (int kg = 0; kg < 4; ++kg) {
            float p0 = __expf(s[kg][0] - mn);
            float p1 = __expf(s[kg][1] - mn);
            float p2 = __expf(s[kg][2] - mn);
            float p3 = __expf(s[kg][3] - mn);
            ps += (p0 + p1) + (p2 + p3);
            *(ushort4*)&Ps[qloc * PADP + kg * 16 + quad * 4] =
                make_ushort4(f2b(p0), f2b(p1), f2b(p2), f2b(p3));
        }
        ps += __shfl_xor(ps, 16, 64);
        ps += __shfl_xor(ps, 32, 64);
        l = l * alpha + ps;
        #pragma unroll
        for (int dg = 0; dg < 4; ++dg)
            #pragma unroll
            for (int r = 0; r < 4; ++r) accO[dg][r] *= alpha;

        short8 pb0 = *(const short8*)&Ps[qloc * PADP + quad * 8];
        short8 pb1 = *(const short8*)&Ps[qloc * PADP + 32 + quad * 8];
        #pragma unroll
        for (int dg = 0; dg < 4; ++dg) {
            accO[dg] = __builtin_amdgcn_mfma_f32_16x16x32_bf16(vb[dg][0], pb0, accO[dg], 0, 0, 0);
            accO[dg] = __builtin_amdgcn_mfma_f32_16x16x32_bf16(vb[dg][1], pb1, accO[dg], 0, 0, 0);
        }
    };

    // ---- software pipeline ----
    ushort4 vcur[4], vnxt[4];
    stage_tile(0, 0, NHD);               // K(0) -> Ks[0]
    load_vregs(0, vcur);

    for (int kt = 0; kt <= qtB; ++kt) {
        const int cur = kt & 1, nxt = cur ^ 1;
        __syncthreads();                 // (A) drains K(kt) DMA (aged a phase)
        write_vt(cur, vcur);
        __syncthreads();                 // (B) Vt[cur] visible
        if (kt < qtB) {
            stage_tile(nxt, (kt + 1) * 64, NHD);  // in flight during compute
            load_vregs(kt + 1, vnxt);
        }

        short8 kb[4][2], vb[4][2];
        #pragma unroll
        for (int kg = 0; kg < 4; ++kg) {
            kb[kg][0] = read_frag(cur, kg * 16 + col, 0);
            kb[kg][1] = read_frag(cur, kg * 16 + col, 1);
        }
        #pragma unroll
        for (int dg = 0; dg < 4; ++dg) {
            const int n = dg * 16 + col;
            short4v lo0 = *(const short4v*)&Vt[cur][n * PADV + quad * 8];
            short4v hi0 = *(const short4v*)&Vt[cur][n * PADV + quad * 8 + 4];
            short4v lo1 = *(const short4v*)&Vt[cur][n * PADV + 32 + quad * 8];
            short4v hi1 = *(const short4v*)&Vt[cur][n * PADV + 32 + quad * 8 + 4];
            vb[dg][0] = __builtin_shufflevector(lo0, hi0, 0, 1, 2, 3, 4, 5, 6, 7);
            vb[dg][1] = __builtin_shufflevector(lo1, hi1, 0, 1, 2, 3, 4, 5, 6, 7);
        }

        process(bqB0, bqB1, kb, vb, accB, mB, lB, kt == qtB);
        if (kt <= qtA)
            process(bqA0, bqA1, kb, vb, accA, mA, lA, kt == qtA);

        #pragma unroll
        for (int i = 0; i < 4; ++i) vcur[i] = vnxt[i];
    }

    // ---- epilogue ----
    {
        const float inv = 1.f / lA;
        const size_t rowoff = ((size_t)b * NS + qtA * 64 + qloc) * ND + h * NHD;
        #pragma unroll
        for (int dg = 0; dg < 4; ++dg) {
            ushort4 o;
            o.x = f2b(accA[dg][0] * inv);
            o.y = f2b(accA[dg][1] * inv);
            o.z = f2b(accA[dg][2] * inv);
            o.w = f2b(accA[dg][3] * inv);
            *(ushort4*)(vals + rowoff + dg * 16 + quad * 4) = o;
        }
    }
    {
        const float inv = 1.f / lB;
        const size_t rowoff = ((size_t)b * NS + qtB * 64 + qloc) * ND + h * NHD;
        #pragma unroll
        for (int dg = 0; dg < 4; ++dg) {
            ushort4 o;
            o.x = f2b(accB[dg][0] * inv);
            o.y = f2b(accB[dg][1] * inv);
            o.z = f2b(accB[dg][2] * inv);
            o.w = f2b(accB[dg][3] * inv);
            *(ushort4*)(vals + rowoff + dg * 16 + quad * 4) = o;
        }
    }
}

extern "C" void kernel_launch(void* const* d_in, const int* in_sizes, int n_in,
                              void* d_out, int out_size, void* d_ws, size_t ws_size,
                              hipStream_t stream)
{
    // inputs: x, mask(unused), W_qkv, b_qkv, W_o, b_o  -- all fp32
    const float* x    = (const float*)d_in[0];
    const float* Wqkv = (const float*)d_in[2];
    const float* bqkv = (const float*)d_in[3];
    const float* Wo   = (const float*)d_in[4];
    const float* bo   = (const float*)d_in[5];
    float* out = (float*)d_out;

    u16* x_bf   = (u16*)d_ws;                       //  4096*1024
    u16* WqkvT  = x_bf   + (size_t)4096 * 1024;     //  3072*1024  [N,K]
    u16* WoT    = WqkvT  + (size_t)3072 * 1024;     //  1024*1024  [N,K]
    u16* qkv    = WoT    + (size_t)1024 * 1024;     //  4096*3072
    u16* vals   = qkv    + (size_t)4096 * 3072;     //  4096*1024

    const int M = NB * NS;  // 4096

    convert_bf16<<<dim3(M * ND / (256 * 8)), dim3(256), 0, stream>>>(
        x, x_bf, M * ND);
    transpose_bf16<<<dim3(QLD / 64, ND / 64), dim3(256), 0, stream>>>(
        Wqkv, WqkvT, ND, QLD);
    transpose_bf16<<<dim3(ND / 64, ND / 64), dim3(256), 0, stream>>>(
        Wo, WoT, ND, ND);

    gemm_mfma<true><<<dim3(QLD / 128, M / 128), dim3(256), 0, stream>>>(
        x_bf, WqkvT, bqkv, qkv, M, QLD, ND);
    attn_kernel<<<dim3(16, NB * NH), dim3(256), 0, stream>>>(qkv, vals);
    gemm_mfma<false><<<dim3(ND / 128, M / 128), dim3(256), 0, stream>>>(
        vals, WoT, bo, out, M, ND, ND);
}